// Round 4
// baseline (860.775 us; speedup 1.0000x reference)
//
#include <hip/hip_runtime.h>
#include <hip/hip_bf16.h>

#define N_NODES 131072
#define N_EDGES 262144
#define NBATCH  16

typedef __attribute__((ext_vector_type(8))) __bf16 bf16x8;
typedef __attribute__((ext_vector_type(4))) float  fx4;

__device__ __forceinline__ fx4 mfma16(bf16x8 a, bf16x8 b, fx4 c) {
    return __builtin_amdgcn_mfma_f32_16x16x32_bf16(a, b, c, 0, 0, 0);
}

// load 8 consecutive fp32, convert to bf16x8 (A-fragment k-slice)
__device__ __forceinline__ bf16x8 load_row8(const float* p) {
    const fx4* q = (const fx4*)p;
    fx4 a = q[0], b = q[1];
    bf16x8 r;
    r[0] = (__bf16)a[0]; r[1] = (__bf16)a[1]; r[2] = (__bf16)a[2]; r[3] = (__bf16)a[3];
    r[4] = (__bf16)b[0]; r[5] = (__bf16)b[1]; r[6] = (__bf16)b[2]; r[7] = (__bf16)b[3];
    return r;
}

// ---- rearrange row-major fp32 W[K][128] into bf16 MFMA B-operand order ----
// consumer reads bf16x8 at ((t*KS+ks)*64+lane):
//   B[k = ks*32 + (lane>>4)*8 + j][n = t*16 + (lane&15)]
__global__ void gn_swizzle(const float* __restrict__ src, __bf16* __restrict__ dst, int KS)
{
    int idx = blockIdx.x * 256 + threadIdx.x;
    int total = KS * 32 * 128;
    if (idx >= total) return;
    int j    = idx & 7;
    int lane = (idx >> 3) & 63;
    int rem  = idx >> 9;
    int ks   = rem % KS;
    int t    = rem / KS;
    int n = t * 16 + (lane & 15);
    int k = ks * 32 + ((lane >> 4) << 3) + j;
    dst[idx] = (__bf16)src[k * 128 + n];
}

// ---- edge block: u = MLP(concat(edges, nodes[send], nodes[recv], gl[gid])) ----
__global__ __launch_bounds__(256) void gn_edge_kernel(
    const float* __restrict__ nodes, const float* __restrict__ edges,
    const float* __restrict__ gl,
    const __bf16* __restrict__ W1sw, const float* __restrict__ b1,
    const __bf16* __restrict__ W2sw, const float* __restrict__ b2,
    const float* __restrict__ rn_w,
    const int* __restrict__ senders, const int* __restrict__ receivers,
    const int* __restrict__ egid,
    float* __restrict__ out_edges,
    float* __restrict__ adjacent,
    float* __restrict__ edge_agg)
{
    __shared__ int s_send[128], s_recv[128], s_gid[128];
    __shared__ __align__(16) __bf16 s_H[4][32][152];   // +24 pad: conflict-light
    __shared__ float s_agg[NBATCH * 128];

    const int tid  = threadIdx.x;
    const int wave = tid >> 6, lane = tid & 63;
    const int m = lane & 15, q = lane >> 4;
    const int eblock = blockIdx.x * 128;

    if (tid < 128) {
        int e = eblock + tid;
        s_send[tid] = senders[e];
        s_recv[tid] = receivers[e];
        s_gid[tid]  = egid[e];
    }
    for (int i = tid; i < NBATCH * 128; i += 256) s_agg[i] = 0.f;
    __syncthreads();

    const int wbase = wave * 32;

    // lane owns edge rows wbase+m and wbase+16+m for A-operand reads
    const float* aptr[2][4];
    #pragma unroll
    for (int rt = 0; rt < 2; ++rt) {
        int er = wbase + rt * 16 + m;
        size_t eg = (size_t)(eblock + er);
        aptr[rt][0] = edges + eg * 128;
        aptr[rt][1] = nodes + (size_t)s_send[er] * 128;
        aptr[rt][2] = nodes + (size_t)s_recv[er] * 128;
        aptr[rt][3] = gl    + (size_t)s_gid[er]  * 128;
    }

    fx4 acc[2][8];
    #pragma unroll
    for (int rt = 0; rt < 2; ++rt)
        #pragma unroll
        for (int t = 0; t < 8; ++t) acc[rt][t] = fx4{0.f, 0.f, 0.f, 0.f};

    const bf16x8* W1v = (const bf16x8*)W1sw;
    // GEMM1: K=512, 16 k-steps of 32
    #pragma unroll
    for (int ks = 0; ks < 16; ++ks) {
        const int seg  = ks >> 2;
        const int koff = ((ks & 3) << 5) + (q << 3);
        bf16x8 a0 = load_row8(aptr[0][seg] + koff);
        bf16x8 a1 = load_row8(aptr[1][seg] + koff);
        #pragma unroll
        for (int t = 0; t < 8; ++t) {
            bf16x8 b = W1v[(t * 16 + ks) * 64 + lane];
            acc[0][t] = mfma16(a0, b, acc[0][t]);
            acc[1][t] = mfma16(a1, b, acc[1][t]);
        }
    }

    // bias + relu -> H (bf16) in LDS. C/D map: col=lane&15, row=q*4+r
    #pragma unroll
    for (int t = 0; t < 8; ++t) {
        float bv = b1[t * 16 + m];
        #pragma unroll
        for (int rt = 0; rt < 2; ++rt)
            #pragma unroll
            for (int r = 0; r < 4; ++r) {
                float h = acc[rt][t][r] + bv;
                s_H[wave][rt * 16 + q * 4 + r][t * 16 + m] = (__bf16)fmaxf(h, 0.f);
            }
    }
    __syncthreads();

    #pragma unroll
    for (int rt = 0; rt < 2; ++rt)
        #pragma unroll
        for (int t = 0; t < 8; ++t) acc[rt][t] = fx4{0.f, 0.f, 0.f, 0.f};

    const bf16x8* W2v = (const bf16x8*)W2sw;
    // GEMM2: K=128, 4 k-steps
    #pragma unroll
    for (int ks = 0; ks < 4; ++ks) {
        bf16x8 a0 = *(const bf16x8*)&s_H[wave][m][ks * 32 + q * 8];
        bf16x8 a1 = *(const bf16x8*)&s_H[wave][16 + m][ks * 32 + q * 8];
        #pragma unroll
        for (int t = 0; t < 8; ++t) {
            bf16x8 b = W2v[(t * 4 + ks) * 64 + lane];
            acc[0][t] = mfma16(a0, b, acc[0][t]);
            acc[1][t] = mfma16(a1, b, acc[1][t]);
        }
    }

    const float mres = log1pf(expf(rn_w[0]));

    #pragma unroll
    for (int rt = 0; rt < 2; ++rt) {
        int er0 = wbase + rt * 16 + q * 4;
        bool sameg = (s_gid[er0] == s_gid[er0 + 3]);
        #pragma unroll
        for (int t = 0; t < 8; ++t) {
            int col = t * 16 + m;
            float bv = b2[col];
            float usum = 0.f;
            #pragma unroll
            for (int r = 0; r < 4; ++r) {
                int er = er0 + r;
                size_t eg = (size_t)(eblock + er);
                float u = acc[rt][t][r] + bv;
                out_edges[eg * 128 + col] = edges[eg * 128 + col] + mres * u;
                unsafeAtomicAdd(&adjacent[(size_t)s_recv[er] * 128 + col], u);
                if (sameg) usum += u;
                else       atomicAdd(&s_agg[s_gid[er] * 128 + col], u);
            }
            if (sameg) atomicAdd(&s_agg[s_gid[er0] * 128 + col], usum);
        }
    }
    __syncthreads();
    for (int i = tid; i < NBATCH * 128; i += 256) {
        float v = s_agg[i];
        if (v != 0.f) unsafeAtomicAdd(&edge_agg[i], v);
    }
}

// ---- node block: u = MLP(concat(nodes, adjacent, gl[gid])) ----
__global__ __launch_bounds__(256) void gn_node_kernel(
    const float* __restrict__ nodes,
    const float* __restrict__ gl,
    const __bf16* __restrict__ W1sw, const float* __restrict__ b1,
    const __bf16* __restrict__ W2sw, const float* __restrict__ b2,
    const float* __restrict__ rn_w,
    const int* __restrict__ ngid,
    const float* __restrict__ adjacent,
    float* __restrict__ out_nodes,
    float* __restrict__ node_agg)
{
    __shared__ int s_gid[128];
    __shared__ __align__(16) __bf16 s_H[4][32][152];
    __shared__ float s_agg[NBATCH * 128];

    const int tid  = threadIdx.x;
    const int wave = tid >> 6, lane = tid & 63;
    const int m = lane & 15, q = lane >> 4;
    const int nblock = blockIdx.x * 128;

    if (tid < 128) s_gid[tid] = ngid[nblock + tid];
    for (int i = tid; i < NBATCH * 128; i += 256) s_agg[i] = 0.f;
    __syncthreads();

    const int wbase = wave * 32;
    const float* ap[2][3];
    #pragma unroll
    for (int rt = 0; rt < 2; ++rt) {
        int vr = wbase + rt * 16 + m;
        size_t vg = (size_t)(nblock + vr);
        ap[rt][0] = nodes + vg * 128;
        ap[rt][1] = adjacent + vg * 128;
        ap[rt][2] = gl + (size_t)s_gid[vr] * 128;
    }

    fx4 acc[2][8];
    #pragma unroll
    for (int rt = 0; rt < 2; ++rt)
        #pragma unroll
        for (int t = 0; t < 8; ++t) acc[rt][t] = fx4{0.f, 0.f, 0.f, 0.f};

    const bf16x8* W1v = (const bf16x8*)W1sw;
    // GEMM1: K=384, 12 k-steps (seg 0: nodes, 1: adjacent, 2: global)
    #pragma unroll
    for (int ks = 0; ks < 12; ++ks) {
        const int seg  = ks >> 2;
        const int koff = ((ks & 3) << 5) + (q << 3);
        bf16x8 a0 = load_row8(ap[0][seg] + koff);
        bf16x8 a1 = load_row8(ap[1][seg] + koff);
        #pragma unroll
        for (int t = 0; t < 8; ++t) {
            bf16x8 b = W1v[(t * 12 + ks) * 64 + lane];
            acc[0][t] = mfma16(a0, b, acc[0][t]);
            acc[1][t] = mfma16(a1, b, acc[1][t]);
        }
    }

    #pragma unroll
    for (int t = 0; t < 8; ++t) {
        float bv = b1[t * 16 + m];
        #pragma unroll
        for (int rt = 0; rt < 2; ++rt)
            #pragma unroll
            for (int r = 0; r < 4; ++r) {
                float h = acc[rt][t][r] + bv;
                s_H[wave][rt * 16 + q * 4 + r][t * 16 + m] = (__bf16)fmaxf(h, 0.f);
            }
    }
    __syncthreads();

    #pragma unroll
    for (int rt = 0; rt < 2; ++rt)
        #pragma unroll
        for (int t = 0; t < 8; ++t) acc[rt][t] = fx4{0.f, 0.f, 0.f, 0.f};

    const bf16x8* W2v = (const bf16x8*)W2sw;
    #pragma unroll
    for (int ks = 0; ks < 4; ++ks) {
        bf16x8 a0 = *(const bf16x8*)&s_H[wave][m][ks * 32 + q * 8];
        bf16x8 a1 = *(const bf16x8*)&s_H[wave][16 + m][ks * 32 + q * 8];
        #pragma unroll
        for (int t = 0; t < 8; ++t) {
            bf16x8 b = W2v[(t * 4 + ks) * 64 + lane];
            acc[0][t] = mfma16(a0, b, acc[0][t]);
            acc[1][t] = mfma16(a1, b, acc[1][t]);
        }
    }

    const float mres = log1pf(expf(rn_w[0]));

    #pragma unroll
    for (int rt = 0; rt < 2; ++rt) {
        int vr0 = wbase + rt * 16 + q * 4;
        bool sameg = (s_gid[vr0] == s_gid[vr0 + 3]);
        #pragma unroll
        for (int t = 0; t < 8; ++t) {
            int col = t * 16 + m;
            float bv = b2[col];
            float usum = 0.f;
            #pragma unroll
            for (int r = 0; r < 4; ++r) {
                int vr = vr0 + r;
                size_t vg = (size_t)(nblock + vr);
                float u = acc[rt][t][r] + bv;
                out_nodes[vg * 128 + col] = nodes[vg * 128 + col] + mres * u;
                if (sameg) usum += u;
                else       atomicAdd(&s_agg[s_gid[vr] * 128 + col], u);
            }
            if (sameg) atomicAdd(&s_agg[s_gid[vr0] * 128 + col], usum);
        }
    }
    __syncthreads();
    for (int i = tid; i < NBATCH * 128; i += 256) {
        float v = s_agg[i];
        if (v != 0.f) unsafeAtomicAdd(&node_agg[i], v);
    }
}

// ---- global block: tiny MLP in fp32, 16 blocks x 128 threads ----
__global__ void gn_global_kernel(
    const float* __restrict__ gl,
    const float* __restrict__ gW1, const float* __restrict__ gb1,
    const float* __restrict__ gW2, const float* __restrict__ gb2,
    const float* __restrict__ rn_w,
    const float* __restrict__ node_agg, const float* __restrict__ edge_agg,
    float* __restrict__ out_gl)
{
    __shared__ float s_x[384];
    __shared__ float s_h[128];
    const int row = blockIdx.x, t = threadIdx.x;

    s_x[t]       = node_agg[row * 128 + t];
    s_x[128 + t] = edge_agg[row * 128 + t];
    s_x[256 + t] = gl[row * 128 + t];
    __syncthreads();

    float acc = gb1[t];
    for (int k = 0; k < 384; ++k) acc += s_x[k] * gW1[k * 128 + t];
    s_h[t] = fmaxf(acc, 0.f);
    __syncthreads();

    float acc2 = gb2[t];
    for (int k = 0; k < 128; ++k) acc2 += s_h[k] * gW2[k * 128 + t];
    const float mres = log1pf(expf(rn_w[0]));
    out_gl[row * 128 + t] = gl[row * 128 + t] + mres * acc2;
}

extern "C" void kernel_launch(void* const* d_in, const int* in_sizes, int n_in,
                              void* d_out, int out_size, void* d_ws, size_t ws_size,
                              hipStream_t stream)
{
    const float* nodes = (const float*)d_in[0];
    const float* edges = (const float*)d_in[1];
    const float* gl    = (const float*)d_in[2];
    const float* eW1   = (const float*)d_in[3];
    const float* eb1   = (const float*)d_in[4];
    const float* eW2   = (const float*)d_in[5];
    const float* eb2   = (const float*)d_in[6];
    const float* nW1   = (const float*)d_in[7];
    const float* nb1   = (const float*)d_in[8];
    const float* nW2   = (const float*)d_in[9];
    const float* nb2   = (const float*)d_in[10];
    const float* gW1   = (const float*)d_in[11];
    const float* gb1   = (const float*)d_in[12];
    const float* gW2   = (const float*)d_in[13];
    const float* gb2   = (const float*)d_in[14];
    const float* rn_w  = (const float*)d_in[15];
    const int* receivers = (const int*)d_in[16];
    const int* senders   = (const int*)d_in[17];
    const int* ngid      = (const int*)d_in[18];
    const int* egid      = (const int*)d_in[19];

    char* ws = (char*)d_ws;
    __bf16* eW1sw    = (__bf16*)(ws + 0);                // 131072 B
    __bf16* eW2sw    = (__bf16*)(ws + 131072);           // 32768 B
    __bf16* nW1sw    = (__bf16*)(ws + 163840);           // 98304 B
    __bf16* nW2sw    = (__bf16*)(ws + 262144);           // 32768 B
    float*  edge_agg = (float*)(ws + 294912);            // 8192 B
    float*  node_agg = (float*)(ws + 303104);            // 8192 B
    float*  adjacent = (float*)(ws + 311296);            // 67108864 B

    float* out_nodes = (float*)d_out;
    float* out_edges = out_nodes + (size_t)N_NODES * 128;
    float* out_gl    = out_edges + (size_t)N_EDGES * 128;

    // zero aggs + adjacent (ws is poisoned 0xAA before every launch)
    hipMemsetAsync(ws + 294912, 0, (size_t)16384 + 67108864, stream);

    gn_swizzle<<<dim3(256), dim3(256), 0, stream>>>(eW1, eW1sw, 16);
    gn_swizzle<<<dim3(64),  dim3(256), 0, stream>>>(eW2, eW2sw, 4);
    gn_swizzle<<<dim3(192), dim3(256), 0, stream>>>(nW1, nW1sw, 12);
    gn_swizzle<<<dim3(64),  dim3(256), 0, stream>>>(nW2, nW2sw, 4);

    gn_edge_kernel<<<dim3(N_EDGES / 128), dim3(256), 0, stream>>>(
        nodes, edges, gl, eW1sw, eb1, eW2sw, eb2, rn_w,
        senders, receivers, egid, out_edges, adjacent, edge_agg);

    gn_node_kernel<<<dim3(N_NODES / 128), dim3(256), 0, stream>>>(
        nodes, gl, nW1sw, nb1, nW2sw, nb2, rn_w,
        ngid, adjacent, out_nodes, node_agg);

    gn_global_kernel<<<dim3(NBATCH), dim3(128), 0, stream>>>(
        gl, gW1, gb1, gW2, gb2, rn_w, node_agg, edge_agg, out_gl);
}